// Round 18
// baseline (183.960 us; speedup 1.0000x reference)
//
#include <hip/hip_runtime.h>
#include <hip/hip_bf16.h>

// Swin-V2 window attention, fused. B=2048 windows, N=64 tokens, C=256, H=8, Dh=32.
// R18 = R17 with compile fix (__exp2f -> exp2f; HIP device exp2f lowers to bare
// v_exp_f32). Changes vs R16 (178.1us, PASS):
//   1. log2-domain softmax: scale/rpb pre-multiplied by log2(e) in the expand
//      kernel; exp2f (bare v_exp_f32) replaces __expf (mul+exp). Softmax ratio
//      invariant under base change; max-subtract kept (2^x overflow guard).
//   2. QKV k-loop unroll 4 ALONE (deconfounds R13, whose regression bundled
//      setprio — the documented-negative half). proj stays unroll 2, no setprio.
// EVIDENCE RULES (R3..R16):
//  - never feed RAW MFMA-accumulator values to inline-asm v_cvt_pk_bf16_f32
//    (0.119 absmax R6/R7). pkc (compiler-native) on acc values is safe (R15);
//    permlane inline-asm on pkc outputs is safe (R16).
//  - never use __launch_bounds__ minWavesPerEU >= 3 (NaN with AND without cvt2).
//  - occupancy is register-capped at 2 blocks/CU; lb stays (256,2).
//  - deferred-V global x re-read thrashes L2 (R8) — x staged once in LDS.
//  - LDS bank counter now at b128 wide-op floor (5.2M, R16). Don't swizzle.
//  - setprio: regression on this kernel (R13+m190).
// Layout algebra (mfma_f32_16x16x32_bf16): C/D: col=lane&15, row=(lane>>4)*4+reg;
// A-frag A[lane&15][(lane>>4)*8+j]; B-frag B[(lane>>4)*8+j][lane&15].
// xposeP: swap32+swap16 pairs give out[w] <- in[lg>>1][w&1] @ group 2(lg&1)+(w>>1).

typedef __attribute__((ext_vector_type(8))) short bf16x8;
typedef __attribute__((ext_vector_type(4))) short short4v;
typedef __attribute__((ext_vector_type(4))) float f32x4;

__device__ __forceinline__ unsigned short f2bf(float f) {
  union { float f; unsigned int u; } a; a.f = f;
  return (unsigned short)((a.u + 0x7FFFu + ((a.u >> 16) & 1u)) >> 16);  // RNE
}

// compiler-native packed f32x2 -> bf16x2 (RNE, lo = first/low 16b). Safe on
// accumulator values: no inline asm, compiler manages register classes.
__device__ __forceinline__ unsigned pkc(float lo, float hi) {
  float2 f; f.x = lo; f.y = hi;
  __hip_bfloat162 h = __float22bfloat162_rn(f);
  union { __hip_bfloat162 h; unsigned u; } c; c.h = h;
  return c.u;
}

// packed f32x2 -> bf16x2 inline asm, single VALU instr. ONLY safe on plain-VGPR
// load-path values — see EVIDENCE RULES above.
__device__ __forceinline__ unsigned int cvt2(float lo, float hi) {
  unsigned int r;
  asm("v_cvt_pk_bf16_f32 %0, %1, %2" : "=v"(r) : "v"(lo), "v"(hi));
  return r;
}

// 4x4 u32 transpose across stride-16 lane groups via permlane swaps (VALU).
// R16-proven (PASS, absmax 0.001953).
__device__ __forceinline__ bf16x8 xposeP(unsigned a0, unsigned a1,
                                         unsigned b0, unsigned b1) {
  asm("v_permlane32_swap_b32 %0, %1" : "+v"(a0), "+v"(b0));
  asm("v_permlane16_swap_b32 %0, %1" : "+v"(a0), "+v"(b0));
  asm("v_permlane32_swap_b32 %0, %1" : "+v"(a1), "+v"(b1));
  asm("v_permlane16_swap_b32 %0, %1" : "+v"(a1), "+v"(b1));
  union { unsigned u[4]; bf16x8 v; } c;
  c.u[0] = a0; c.u[1] = a1; c.u[2] = b0; c.u[3] = b1;
  return c.v;
}

// ---------------- fused prep: cpb table (blocks 0..126) + weight convert ----------------
__global__ void prep_kernel(const float* __restrict__ w1, const float* __restrict__ b1,
                            const float* __restrict__ w2, float* __restrict__ bt,
                            const float* __restrict__ qw, const float* __restrict__ pw,
                            const float* __restrict__ qb, const float* __restrict__ vb,
                            short* __restrict__ wqkv, short* __restrict__ wproj,
                            float* __restrict__ qkvb)
{
  if (blockIdx.x < 127) {
    // ---- CPB MLP table row (R9-proven body, first wave only) ----
    if (threadIdx.x < 64) {
      const int row = blockIdx.x;       // 0..126
      const int lane = threadIdx.x;     // 0..63
      float xr = ((float)row - 63.0f) * (8.0f / 63.0f);
      float sgn = (xr > 0.0f) ? 1.0f : ((xr < 0.0f) ? -1.0f : 0.0f);
      float val = sgn * log2f(fabsf(xr) + 1.0f) * (1.0f / 3.0f);  // /log2(8)
      float acc[8];
      #pragma unroll
      for (int hh = 0; hh < 8; ++hh) acc[hh] = 0.0f;
      #pragma unroll
      for (int jj = 0; jj < 8; ++jj) {
        int j = jj * 64 + lane;
        float hv = fmaxf(val * w1[j] + b1[j], 0.0f);
        #pragma unroll
        for (int hh = 0; hh < 8; ++hh) acc[hh] += hv * w2[hh * 512 + j];
      }
      #pragma unroll
      for (int hh = 0; hh < 8; ++hh) {
        #pragma unroll
        for (int m = 1; m < 64; m <<= 1) acc[hh] += __shfl_xor(acc[hh], m);
      }
      if (lane == 0) {
        #pragma unroll
        for (int hh = 0; hh < 8; ++hh) bt[row * 8 + hh] = acc[hh];
      }
    }
  } else {
    // ---- weight conversion (proven formulas, re-based index) ----
    const int idx = (blockIdx.x - 127) * 256 + threadIdx.x;
    if (idx < 196608) wqkv[idx] = (short)f2bf(qw[idx]);
    else if (idx - 196608 < 65536) wproj[idx - 196608] = (short)f2bf(pw[idx - 196608]);
    if (idx < 768) qkvb[idx] = (idx < 256) ? qb[idx] : ((idx < 512) ? 0.0f : vb[idx - 512]);
  }
}

// ---- expand (S^T orientation): rpb[h][mt][nt][lane][r] = 16*sigmoid(b)*LOG2E;
//      scale[h] = exp(min(ls,ln100))*LOG2E  (log2-domain softmax inputs) ----
__global__ void cpb_expand_kernel(const float* __restrict__ bt, const float* __restrict__ ls,
                                  float* __restrict__ rpb, float* __restrict__ scale)
{
  const float LOG2E = 1.4426950408889634f;
  const int i = blockIdx.x * 256 + threadIdx.x;   // 0..32767
  const int r = i & 3, lane = (i >> 2) & 63, nt = (i >> 8) & 3, mt = (i >> 10) & 3, hh = i >> 12;
  const int row_i = mt * 16 + (lane & 15);          // query index
  const int col_j = nt * 16 + (lane >> 4) * 4 + r;  // key index
  float b = bt[(row_i - col_j + 63) * 8 + hh];
  rpb[i] = LOG2E * 16.0f / (1.0f + __expf(-b));
  if (i < 8) scale[i] = LOG2E * __expf(fminf(ls[i], 4.605170185988091f));  // ln(100)
}

// ---------------- fused window attention ----------------
__global__ __launch_bounds__(256, 2) void win_attn_kernel(
    const float* __restrict__ x,
    const short* __restrict__ wqkv,
    const short* __restrict__ wproj,
    const float* __restrict__ qkvb,
    const float* __restrict__ scale,
    const float* __restrict__ rpb,
    const float* __restrict__ projb,
    float* __restrict__ out)
{
  // single 33,792 B buffer: x tile bf16 [token][C] stride 264 during QKV;
  // overlaid by attention-output tile ob (same layout) after the hi loop.
  __shared__ short sbuf[64 * 264];

  const int tid = threadIdx.x;
  const int wid = tid >> 6;
  const int lane = tid & 63;
  const int lq = lane & 15;
  const int lg = lane >> 4;
  const int blk = blockIdx.x;

  const f32x4 fz = {0.0f, 0.0f, 0.0f, 0.0f};

  // ---- stage x tile (64x256 f32 -> bf16 LDS; cvt2 on load path; bank-floor clean) ----
  {
    const int r = tid >> 2;
    const int c0 = (tid & 3) * 64;
    const float4* xg = (const float4*)(x + ((size_t)blk * 64 + r) * 256 + c0);
    short* dst = &sbuf[r * 264 + c0];
    #pragma unroll
    for (int i = 0; i < 16; i += 2) {
      float4 a = xg[i];
      float4 b = xg[i + 1];
      union { unsigned int u[4]; bf16x8 v; } c;
      c.u[0] = cvt2(a.x, a.y); c.u[1] = cvt2(a.z, a.w);
      c.u[2] = cvt2(b.x, b.y); c.u[3] = cvt2(b.z, b.w);
      *(bf16x8*)(dst + i * 4) = c.v;
    }
  }
  __syncthreads();

  f32x4 otk[2][2][4];   // [hi][dt][mt], hi compile-time (R2-proven epilogue hold)

  #pragma unroll
  for (int hi = 0; hi < 2; ++hi) {
    const int h = wid + hi * 4;
    const short* wqb = wqkv + (h * 32 + lq) * 256 + lg * 8;

    // ---- QKV: sq/sk = W · x^T (q^T,k^T C-layout), sv = x · Wv^T (v C-layout) ----
    f32x4 sq[2][4], sk[2][4], sv[4][2];
    #pragma unroll
    for (int i = 0; i < 2; ++i)
      #pragma unroll
      for (int j = 0; j < 4; ++j) { sq[i][j] = fz; sk[i][j] = fz; sv[j][i] = fz; }

    #pragma unroll 4
    for (int ks = 0; ks < 8; ++ks) {
      const int k0 = ks * 32;
      bf16x8 xf[4];
      #pragma unroll
      for (int mt = 0; mt < 4; ++mt)
        xf[mt] = *(const bf16x8*)&sbuf[(mt * 16 + lq) * 264 + k0 + lg * 8];
      bf16x8 wqf[2], wkf[2], wvf[2];
      #pragma unroll
      for (int dt = 0; dt < 2; ++dt) {
        const short* wp = wqb + dt * 4096 + k0;
        wqf[dt] = *(const bf16x8*)wp;
        wkf[dt] = *(const bf16x8*)(wp + 65536);    // +256 rows
        wvf[dt] = *(const bf16x8*)(wp + 131072);   // +512 rows
      }
      #pragma unroll
      for (int dt = 0; dt < 2; ++dt)
        #pragma unroll
        for (int mt = 0; mt < 4; ++mt) {
          sq[dt][mt] = __builtin_amdgcn_mfma_f32_16x16x32_bf16(wqf[dt], xf[mt], sq[dt][mt], 0, 0, 0);
          sk[dt][mt] = __builtin_amdgcn_mfma_f32_16x16x32_bf16(wkf[dt], xf[mt], sk[dt][mt], 0, 0, 0);
          sv[mt][dt] = __builtin_amdgcn_mfma_f32_16x16x32_bf16(xf[mt], wvf[dt], sv[mt][dt], 0, 0, 0);
        }
    }

    bf16x8 qB[4], kA[4], vA[2][2];

    // ---- q: +bias, L2-normalize over d (in-lane 8 + shfl 16/32), pack -> B-frags ----
    {
      float qbias[2][4];
      #pragma unroll
      for (int dt = 0; dt < 2; ++dt)
        #pragma unroll
        for (int r = 0; r < 4; ++r)
          qbias[dt][r] = qkvb[h * 32 + dt * 16 + lg * 4 + r];
      #pragma unroll
      for (int mt = 0; mt < 4; ++mt) {
        float vv[2][4];
        float ss = 0.0f;
        #pragma unroll
        for (int dt = 0; dt < 2; ++dt)
          #pragma unroll
          for (int r = 0; r < 4; ++r) {
            vv[dt][r] = sq[dt][mt][r] + qbias[dt][r];
            ss += vv[dt][r] * vv[dt][r];
          }
        ss += __shfl_xor(ss, 16);
        ss += __shfl_xor(ss, 32);
        float rn = 1.0f / fmaxf(sqrtf(ss), 1e-12f);
        qB[mt] = xposeP(pkc(vv[0][0] * rn, vv[0][1] * rn), pkc(vv[0][2] * rn, vv[0][3] * rn),
                        pkc(vv[1][0] * rn, vv[1][1] * rn), pkc(vv[1][2] * rn, vv[1][3] * rn));
      }
    }
    // ---- k: L2-normalize (bias 0), pack -> A-frags ----
    {
      #pragma unroll
      for (int nt = 0; nt < 4; ++nt) {
        float ss = 0.0f;
        #pragma unroll
        for (int dt = 0; dt < 2; ++dt)
          #pragma unroll
          for (int r = 0; r < 4; ++r) ss += sk[dt][nt][r] * sk[dt][nt][r];
        ss += __shfl_xor(ss, 16);
        ss += __shfl_xor(ss, 32);
        float rn = 1.0f / fmaxf(sqrtf(ss), 1e-12f);
        kA[nt] = xposeP(pkc(sk[0][nt][0] * rn, sk[0][nt][1] * rn), pkc(sk[0][nt][2] * rn, sk[0][nt][3] * rn),
                        pkc(sk[1][nt][0] * rn, sk[1][nt][1] * rn), pkc(sk[1][nt][2] * rn, sk[1][nt][3] * rn));
      }
    }
    // ---- v: +bias, pack -> v^T A-frags vA[dt][kt] ----
    {
      const float vb0 = qkvb[512 + h * 32 + lq];
      const float vb1 = qkvb[512 + h * 32 + 16 + lq];
      unsigned vp[4][2][2];
      #pragma unroll
      for (int mt = 0; mt < 4; ++mt) {
        vp[mt][0][0] = pkc(sv[mt][0][0] + vb0, sv[mt][0][1] + vb0);
        vp[mt][0][1] = pkc(sv[mt][0][2] + vb0, sv[mt][0][3] + vb0);
        vp[mt][1][0] = pkc(sv[mt][1][0] + vb1, sv[mt][1][1] + vb1);
        vp[mt][1][1] = pkc(sv[mt][1][2] + vb1, sv[mt][1][3] + vb1);
      }
      #pragma unroll
      for (int dt = 0; dt < 2; ++dt)
        #pragma unroll
        for (int kt = 0; kt < 2; ++kt)
          vA[dt][kt] = xposeP(vp[2 * kt][dt][0], vp[2 * kt][dt][1],
                              vp[2 * kt + 1][dt][0], vp[2 * kt + 1][dt][1]);
    }

    // ---- S^T[key][query] = mfma(kA, qB) ----
    f32x4 sT[4][4];
    #pragma unroll
    for (int nt = 0; nt < 4; ++nt)
      #pragma unroll
      for (int mt = 0; mt < 4; ++mt)
        sT[nt][mt] = __builtin_amdgcn_mfma_f32_16x16x32_bf16(kA[nt], qB[mt], fz, 0, 0, 0);

    // ---- softmax over keys, LOG2 DOMAIN (sch/rp pre-scaled by log2e);
    //      P packed UNNORMALIZED, inv applied to otk after PV ----
    const float sch = scale[h];
    float invs[4];
    unsigned pp[4][4][2];   // [mt][nt][c]
    #pragma unroll
    for (int mt = 0; mt < 4; ++mt) {
      f32x4 rp[4];
      #pragma unroll
      for (int nt = 0; nt < 4; ++nt)
        rp[nt] = ((const f32x4*)rpb)[((h * 4 + mt) * 4 + nt) * 64 + lane];
      float ee[4][4];
      float mx = -3.0e38f;
      #pragma unroll
      for (int nt = 0; nt < 4; ++nt)
        #pragma unroll
        for (int r = 0; r < 4; ++r) {
          float vv = sT[nt][mt][r] * sch + rp[nt][r];
          ee[nt][r] = vv;
          mx = fmaxf(mx, vv);
        }
      mx = fmaxf(mx, __shfl_xor(mx, 16));
      mx = fmaxf(mx, __shfl_xor(mx, 32));
      float sm = 0.0f;
      #pragma unroll
      for (int nt = 0; nt < 4; ++nt)
        #pragma unroll
        for (int r = 0; r < 4; ++r) {
          ee[nt][r] = exp2f(ee[nt][r] - mx);
          sm += ee[nt][r];
        }
      sm += __shfl_xor(sm, 16);
      sm += __shfl_xor(sm, 32);
      invs[mt] = 1.0f / sm;
      #pragma unroll
      for (int nt = 0; nt < 4; ++nt) {
        pp[mt][nt][0] = pkc(ee[nt][0], ee[nt][1]);
        pp[mt][nt][1] = pkc(ee[nt][2], ee[nt][3]);
      }
    }

    // ---- PV: out^T = v^T · P^T -> otk[hi] (held in regs), then scale by invs ----
    #pragma unroll
    for (int dt = 0; dt < 2; ++dt)
      #pragma unroll
      for (int mt = 0; mt < 4; ++mt) otk[hi][dt][mt] = fz;
    #pragma unroll
    for (int kt = 0; kt < 2; ++kt) {
      bf16x8 pB[4];
      #pragma unroll
      for (int mt = 0; mt < 4; ++mt)
        pB[mt] = xposeP(pp[mt][2 * kt][0], pp[mt][2 * kt][1],
                        pp[mt][2 * kt + 1][0], pp[mt][2 * kt + 1][1]);
      #pragma unroll
      for (int dt = 0; dt < 2; ++dt)
        #pragma unroll
        for (int mt = 0; mt < 4; ++mt)
          otk[hi][dt][mt] = __builtin_amdgcn_mfma_f32_16x16x32_bf16(vA[dt][kt], pB[mt], otk[hi][dt][mt], 0, 0, 0);
    }
    #pragma unroll
    for (int dt = 0; dt < 2; ++dt)
      #pragma unroll
      for (int mt = 0; mt < 4; ++mt)
        otk[hi][dt][mt] = otk[hi][dt][mt] * invs[mt];
  }  // hi

  // ---- all xb reads done: overlay ob on sbuf (compiler-native packs) ----
  __syncthreads();
  #pragma unroll
  for (int hi = 0; hi < 2; ++hi) {
    const int h = wid + hi * 4;
    #pragma unroll
    for (int dt = 0; dt < 2; ++dt)
      #pragma unroll
      for (int mt = 0; mt < 4; ++mt) {
        union { unsigned u[2]; short4v s; } pk;
        pk.u[0] = pkc(otk[hi][dt][mt][0], otk[hi][dt][mt][1]);
        pk.u[1] = pkc(otk[hi][dt][mt][2], otk[hi][dt][mt][3]);
        *(short4v*)&sbuf[(mt * 16 + lq) * 264 + h * 32 + dt * 16 + lg * 4] = pk.s;
      }
  }
  __syncthreads();

  // ---- proj: out = ob · Wp^T + b (wave w -> cols [w*64, w*64+64)) ----
  {
    f32x4 acc[4][4];
    #pragma unroll
    for (int mt = 0; mt < 4; ++mt)
      #pragma unroll
      for (int nt = 0; nt < 4; ++nt) acc[mt][nt] = fz;
    const int c0 = wid * 64;
    #pragma unroll 2
    for (int ks = 0; ks < 8; ++ks) {
      const int k0 = ks * 32;
      bf16x8 a[4], b[4];
      #pragma unroll
      for (int mt = 0; mt < 4; ++mt)
        a[mt] = *(const bf16x8*)&sbuf[(mt * 16 + lq) * 264 + k0 + lg * 8];
      #pragma unroll
      for (int nt = 0; nt < 4; ++nt)
        b[nt] = *(const bf16x8*)&wproj[(c0 + nt * 16 + lq) * 256 + k0 + lg * 8];
      #pragma unroll
      for (int mt = 0; mt < 4; ++mt)
        #pragma unroll
        for (int nt = 0; nt < 4; ++nt)
          acc[mt][nt] = __builtin_amdgcn_mfma_f32_16x16x32_bf16(a[mt], b[nt], acc[mt][nt], 0, 0, 0);
    }
    #pragma unroll
    for (int nt = 0; nt < 4; ++nt) {
      const float pbv = projb[c0 + nt * 16 + lq];
      #pragma unroll
      for (int mt = 0; mt < 4; ++mt)
        #pragma unroll
        for (int r = 0; r < 4; ++r) {
          const int row = mt * 16 + lg * 4 + r;
          out[((size_t)blk * 64 + row) * 256 + c0 + nt * 16 + lq] = acc[mt][nt][r] + pbv;
        }
    }
  }
}

extern "C" void kernel_launch(void* const* d_in, const int* in_sizes, int n_in,
                              void* d_out, int out_size, void* d_ws, size_t ws_size,
                              hipStream_t stream) {
  const float* x     = (const float*)d_in[0];
  const float* qkvw  = (const float*)d_in[1];
  const float* qbias = (const float*)d_in[2];
  const float* vbias = (const float*)d_in[3];
  const float* ls    = (const float*)d_in[4];
  const float* w1    = (const float*)d_in[5];
  const float* b1    = (const float*)d_in[6];
  const float* w2    = (const float*)d_in[7];
  const float* pw    = (const float*)d_in[8];
  const float* pbias = (const float*)d_in[9];
  float* out = (float*)d_out;

  char* ws = (char*)d_ws;
  short* wqkv_bf  = (short*)(ws);                 // 393216 B
  short* wproj_bf = (short*)(ws + 393216);        // 131072 B
  float* rpb      = (float*)(ws + 524288);        // 131072 B
  float* scale    = (float*)(ws + 655360);        // 32 B
  float* qkvb     = (float*)(ws + 655392);        // 3072 B
  float* bt       = (float*)(ws + 658464);        // 4064 B

  prep_kernel<<<dim3(1151), dim3(256), 0, stream>>>(w1, b1, w2, bt,
                                                    qkvw, pw, qbias, vbias,
                                                    wqkv_bf, wproj_bf, qkvb);
  cpb_expand_kernel<<<dim3(128), dim3(256), 0, stream>>>(bt, ls, rpb, scale);
  win_attn_kernel<<<dim3(2048), dim3(256), 0, stream>>>(x, wqkv_bf, wproj_bf, qkvb,
                                                        scale, rpb, pbias, out);
}

// Round 19
// 183.916 us; speedup vs baseline: 1.0002x; 1.0002x over previous
//
#include <hip/hip_runtime.h>
#include <hip/hip_bf16.h>

// Swin-V2 window attention, fused. B=2048 windows, N=64 tokens, C=256, H=8, Dh=32.
// R19 = R16 (178.1us, PASS, best) + log2-domain softmax ALONE (QKV loop back to
// unroll 2). R18 bundled {log2 + unroll4} and regressed to 184.0 with VALUBusy
// 28.5->31.8, VGPR 108->116; unroll>2 is now implicated in BOTH regressions
// (R13: unroll4+setprio, R18: unroll4+log2) -> rule: never unroll>2 here.
//   log2 softmax: scale/rpb pre-multiplied by log2(e) in the expand kernel;
//   exp2f (bare v_exp_f32) replaces __expf (mul+exp). Ratio invariant; max-
//   subtract kept (2^x overflow guard). Saves 128 v_mul/thread.
// EVIDENCE RULES (R3..R18):
//  - never feed RAW MFMA-accumulator values to inline-asm v_cvt_pk_bf16_f32
//    (0.119 absmax R6/R7). pkc (compiler-native) on acc values is safe (R15);
//    permlane inline-asm on pkc outputs is safe (R16).
//  - never use __launch_bounds__ minWavesPerEU >= 3 (NaN with AND without cvt2).
//  - never unroll>2 the QKV k-loop (R13, R18 regressions); no setprio (R13).
//  - occupancy is register-capped at 2 blocks/CU; lb stays (256,2).
//  - deferred-V global x re-read thrashes L2 (R8) — x staged once in LDS.
//  - LDS bank counter at b128 wide-op floor (5.2M, R16). Don't swizzle.
// Layout algebra (mfma_f32_16x16x32_bf16): C/D: col=lane&15, row=(lane>>4)*4+reg;
// A-frag A[lane&15][(lane>>4)*8+j]; B-frag B[(lane>>4)*8+j][lane&15].
// xposeP: swap32+swap16 pairs give out[w] <- in[lg>>1][w&1] @ group 2(lg&1)+(w>>1).

typedef __attribute__((ext_vector_type(8))) short bf16x8;
typedef __attribute__((ext_vector_type(4))) short short4v;
typedef __attribute__((ext_vector_type(4))) float f32x4;

__device__ __forceinline__ unsigned short f2bf(float f) {
  union { float f; unsigned int u; } a; a.f = f;
  return (unsigned short)((a.u + 0x7FFFu + ((a.u >> 16) & 1u)) >> 16);  // RNE
}

// compiler-native packed f32x2 -> bf16x2 (RNE, lo = first/low 16b). Safe on
// accumulator values: no inline asm, compiler manages register classes.
__device__ __forceinline__ unsigned pkc(float lo, float hi) {
  float2 f; f.x = lo; f.y = hi;
  __hip_bfloat162 h = __float22bfloat162_rn(f);
  union { __hip_bfloat162 h; unsigned u; } c; c.h = h;
  return c.u;
}

// packed f32x2 -> bf16x2 inline asm, single VALU instr. ONLY safe on plain-VGPR
// load-path values — see EVIDENCE RULES above.
__device__ __forceinline__ unsigned int cvt2(float lo, float hi) {
  unsigned int r;
  asm("v_cvt_pk_bf16_f32 %0, %1, %2" : "=v"(r) : "v"(lo), "v"(hi));
  return r;
}

// 4x4 u32 transpose across stride-16 lane groups via permlane swaps (VALU).
// R16-proven (PASS, absmax 0.001953).
__device__ __forceinline__ bf16x8 xposeP(unsigned a0, unsigned a1,
                                         unsigned b0, unsigned b1) {
  asm("v_permlane32_swap_b32 %0, %1" : "+v"(a0), "+v"(b0));
  asm("v_permlane16_swap_b32 %0, %1" : "+v"(a0), "+v"(b0));
  asm("v_permlane32_swap_b32 %0, %1" : "+v"(a1), "+v"(b1));
  asm("v_permlane16_swap_b32 %0, %1" : "+v"(a1), "+v"(b1));
  union { unsigned u[4]; bf16x8 v; } c;
  c.u[0] = a0; c.u[1] = a1; c.u[2] = b0; c.u[3] = b1;
  return c.v;
}

// ---------------- fused prep: cpb table (blocks 0..126) + weight convert ----------------
__global__ void prep_kernel(const float* __restrict__ w1, const float* __restrict__ b1,
                            const float* __restrict__ w2, float* __restrict__ bt,
                            const float* __restrict__ qw, const float* __restrict__ pw,
                            const float* __restrict__ qb, const float* __restrict__ vb,
                            short* __restrict__ wqkv, short* __restrict__ wproj,
                            float* __restrict__ qkvb)
{
  if (blockIdx.x < 127) {
    // ---- CPB MLP table row (R9-proven body, first wave only) ----
    if (threadIdx.x < 64) {
      const int row = blockIdx.x;       // 0..126
      const int lane = threadIdx.x;     // 0..63
      float xr = ((float)row - 63.0f) * (8.0f / 63.0f);
      float sgn = (xr > 0.0f) ? 1.0f : ((xr < 0.0f) ? -1.0f : 0.0f);
      float val = sgn * log2f(fabsf(xr) + 1.0f) * (1.0f / 3.0f);  // /log2(8)
      float acc[8];
      #pragma unroll
      for (int hh = 0; hh < 8; ++hh) acc[hh] = 0.0f;
      #pragma unroll
      for (int jj = 0; jj < 8; ++jj) {
        int j = jj * 64 + lane;
        float hv = fmaxf(val * w1[j] + b1[j], 0.0f);
        #pragma unroll
        for (int hh = 0; hh < 8; ++hh) acc[hh] += hv * w2[hh * 512 + j];
      }
      #pragma unroll
      for (int hh = 0; hh < 8; ++hh) {
        #pragma unroll
        for (int m = 1; m < 64; m <<= 1) acc[hh] += __shfl_xor(acc[hh], m);
      }
      if (lane == 0) {
        #pragma unroll
        for (int hh = 0; hh < 8; ++hh) bt[row * 8 + hh] = acc[hh];
      }
    }
  } else {
    // ---- weight conversion (proven formulas, re-based index) ----
    const int idx = (blockIdx.x - 127) * 256 + threadIdx.x;
    if (idx < 196608) wqkv[idx] = (short)f2bf(qw[idx]);
    else if (idx - 196608 < 65536) wproj[idx - 196608] = (short)f2bf(pw[idx - 196608]);
    if (idx < 768) qkvb[idx] = (idx < 256) ? qb[idx] : ((idx < 512) ? 0.0f : vb[idx - 512]);
  }
}

// ---- expand (S^T orientation): rpb[h][mt][nt][lane][r] = 16*sigmoid(b)*LOG2E;
//      scale[h] = exp(min(ls,ln100))*LOG2E  (log2-domain softmax inputs) ----
__global__ void cpb_expand_kernel(const float* __restrict__ bt, const float* __restrict__ ls,
                                  float* __restrict__ rpb, float* __restrict__ scale)
{
  const float LOG2E = 1.4426950408889634f;
  const int i = blockIdx.x * 256 + threadIdx.x;   // 0..32767
  const int r = i & 3, lane = (i >> 2) & 63, nt = (i >> 8) & 3, mt = (i >> 10) & 3, hh = i >> 12;
  const int row_i = mt * 16 + (lane & 15);          // query index
  const int col_j = nt * 16 + (lane >> 4) * 4 + r;  // key index
  float b = bt[(row_i - col_j + 63) * 8 + hh];
  rpb[i] = LOG2E * 16.0f / (1.0f + __expf(-b));
  if (i < 8) scale[i] = LOG2E * __expf(fminf(ls[i], 4.605170185988091f));  // ln(100)
}

// ---------------- fused window attention ----------------
__global__ __launch_bounds__(256, 2) void win_attn_kernel(
    const float* __restrict__ x,
    const short* __restrict__ wqkv,
    const short* __restrict__ wproj,
    const float* __restrict__ qkvb,
    const float* __restrict__ scale,
    const float* __restrict__ rpb,
    const float* __restrict__ projb,
    float* __restrict__ out)
{
  // single 33,792 B buffer: x tile bf16 [token][C] stride 264 during QKV;
  // overlaid by attention-output tile ob (same layout) after the hi loop.
  __shared__ short sbuf[64 * 264];

  const int tid = threadIdx.x;
  const int wid = tid >> 6;
  const int lane = tid & 63;
  const int lq = lane & 15;
  const int lg = lane >> 4;
  const int blk = blockIdx.x;

  const f32x4 fz = {0.0f, 0.0f, 0.0f, 0.0f};

  // ---- stage x tile (64x256 f32 -> bf16 LDS; cvt2 on load path; bank-floor clean) ----
  {
    const int r = tid >> 2;
    const int c0 = (tid & 3) * 64;
    const float4* xg = (const float4*)(x + ((size_t)blk * 64 + r) * 256 + c0);
    short* dst = &sbuf[r * 264 + c0];
    #pragma unroll
    for (int i = 0; i < 16; i += 2) {
      float4 a = xg[i];
      float4 b = xg[i + 1];
      union { unsigned int u[4]; bf16x8 v; } c;
      c.u[0] = cvt2(a.x, a.y); c.u[1] = cvt2(a.z, a.w);
      c.u[2] = cvt2(b.x, b.y); c.u[3] = cvt2(b.z, b.w);
      *(bf16x8*)(dst + i * 4) = c.v;
    }
  }
  __syncthreads();

  f32x4 otk[2][2][4];   // [hi][dt][mt], hi compile-time (R2-proven epilogue hold)

  #pragma unroll
  for (int hi = 0; hi < 2; ++hi) {
    const int h = wid + hi * 4;
    const short* wqb = wqkv + (h * 32 + lq) * 256 + lg * 8;

    // ---- QKV: sq/sk = W · x^T (q^T,k^T C-layout), sv = x · Wv^T (v C-layout) ----
    f32x4 sq[2][4], sk[2][4], sv[4][2];
    #pragma unroll
    for (int i = 0; i < 2; ++i)
      #pragma unroll
      for (int j = 0; j < 4; ++j) { sq[i][j] = fz; sk[i][j] = fz; sv[j][i] = fz; }

    #pragma unroll 2
    for (int ks = 0; ks < 8; ++ks) {
      const int k0 = ks * 32;
      bf16x8 xf[4];
      #pragma unroll
      for (int mt = 0; mt < 4; ++mt)
        xf[mt] = *(const bf16x8*)&sbuf[(mt * 16 + lq) * 264 + k0 + lg * 8];
      bf16x8 wqf[2], wkf[2], wvf[2];
      #pragma unroll
      for (int dt = 0; dt < 2; ++dt) {
        const short* wp = wqb + dt * 4096 + k0;
        wqf[dt] = *(const bf16x8*)wp;
        wkf[dt] = *(const bf16x8*)(wp + 65536);    // +256 rows
        wvf[dt] = *(const bf16x8*)(wp + 131072);   // +512 rows
      }
      #pragma unroll
      for (int dt = 0; dt < 2; ++dt)
        #pragma unroll
        for (int mt = 0; mt < 4; ++mt) {
          sq[dt][mt] = __builtin_amdgcn_mfma_f32_16x16x32_bf16(wqf[dt], xf[mt], sq[dt][mt], 0, 0, 0);
          sk[dt][mt] = __builtin_amdgcn_mfma_f32_16x16x32_bf16(wkf[dt], xf[mt], sk[dt][mt], 0, 0, 0);
          sv[mt][dt] = __builtin_amdgcn_mfma_f32_16x16x32_bf16(xf[mt], wvf[dt], sv[mt][dt], 0, 0, 0);
        }
    }

    bf16x8 qB[4], kA[4], vA[2][2];

    // ---- q: +bias, L2-normalize over d (in-lane 8 + shfl 16/32), pack -> B-frags ----
    {
      float qbias[2][4];
      #pragma unroll
      for (int dt = 0; dt < 2; ++dt)
        #pragma unroll
        for (int r = 0; r < 4; ++r)
          qbias[dt][r] = qkvb[h * 32 + dt * 16 + lg * 4 + r];
      #pragma unroll
      for (int mt = 0; mt < 4; ++mt) {
        float vv[2][4];
        float ss = 0.0f;
        #pragma unroll
        for (int dt = 0; dt < 2; ++dt)
          #pragma unroll
          for (int r = 0; r < 4; ++r) {
            vv[dt][r] = sq[dt][mt][r] + qbias[dt][r];
            ss += vv[dt][r] * vv[dt][r];
          }
        ss += __shfl_xor(ss, 16);
        ss += __shfl_xor(ss, 32);
        float rn = 1.0f / fmaxf(sqrtf(ss), 1e-12f);
        qB[mt] = xposeP(pkc(vv[0][0] * rn, vv[0][1] * rn), pkc(vv[0][2] * rn, vv[0][3] * rn),
                        pkc(vv[1][0] * rn, vv[1][1] * rn), pkc(vv[1][2] * rn, vv[1][3] * rn));
      }
    }
    // ---- k: L2-normalize (bias 0), pack -> A-frags ----
    {
      #pragma unroll
      for (int nt = 0; nt < 4; ++nt) {
        float ss = 0.0f;
        #pragma unroll
        for (int dt = 0; dt < 2; ++dt)
          #pragma unroll
          for (int r = 0; r < 4; ++r) ss += sk[dt][nt][r] * sk[dt][nt][r];
        ss += __shfl_xor(ss, 16);
        ss += __shfl_xor(ss, 32);
        float rn = 1.0f / fmaxf(sqrtf(ss), 1e-12f);
        kA[nt] = xposeP(pkc(sk[0][nt][0] * rn, sk[0][nt][1] * rn), pkc(sk[0][nt][2] * rn, sk[0][nt][3] * rn),
                        pkc(sk[1][nt][0] * rn, sk[1][nt][1] * rn), pkc(sk[1][nt][2] * rn, sk[1][nt][3] * rn));
      }
    }
    // ---- v: +bias, pack -> v^T A-frags vA[dt][kt] ----
    {
      const float vb0 = qkvb[512 + h * 32 + lq];
      const float vb1 = qkvb[512 + h * 32 + 16 + lq];
      unsigned vp[4][2][2];
      #pragma unroll
      for (int mt = 0; mt < 4; ++mt) {
        vp[mt][0][0] = pkc(sv[mt][0][0] + vb0, sv[mt][0][1] + vb0);
        vp[mt][0][1] = pkc(sv[mt][0][2] + vb0, sv[mt][0][3] + vb0);
        vp[mt][1][0] = pkc(sv[mt][1][0] + vb1, sv[mt][1][1] + vb1);
        vp[mt][1][1] = pkc(sv[mt][1][2] + vb1, sv[mt][1][3] + vb1);
      }
      #pragma unroll
      for (int dt = 0; dt < 2; ++dt)
        #pragma unroll
        for (int kt = 0; kt < 2; ++kt)
          vA[dt][kt] = xposeP(vp[2 * kt][dt][0], vp[2 * kt][dt][1],
                              vp[2 * kt + 1][dt][0], vp[2 * kt + 1][dt][1]);
    }

    // ---- S^T[key][query] = mfma(kA, qB) ----
    f32x4 sT[4][4];
    #pragma unroll
    for (int nt = 0; nt < 4; ++nt)
      #pragma unroll
      for (int mt = 0; mt < 4; ++mt)
        sT[nt][mt] = __builtin_amdgcn_mfma_f32_16x16x32_bf16(kA[nt], qB[mt], fz, 0, 0, 0);

    // ---- softmax over keys, LOG2 DOMAIN (sch/rp pre-scaled by log2e);
    //      P packed UNNORMALIZED, inv applied to otk after PV ----
    const float sch = scale[h];
    float invs[4];
    unsigned pp[4][4][2];   // [mt][nt][c]
    #pragma unroll
    for (int mt = 0; mt < 4; ++mt) {
      f32x4 rp[4];
      #pragma unroll
      for (int nt = 0; nt < 4; ++nt)
        rp[nt] = ((const f32x4*)rpb)[((h * 4 + mt) * 4 + nt) * 64 + lane];
      float ee[4][4];
      float mx = -3.0e38f;
      #pragma unroll
      for (int nt = 0; nt < 4; ++nt)
        #pragma unroll
        for (int r = 0; r < 4; ++r) {
          float vv = sT[nt][mt][r] * sch + rp[nt][r];
          ee[nt][r] = vv;
          mx = fmaxf(mx, vv);
        }
      mx = fmaxf(mx, __shfl_xor(mx, 16));
      mx = fmaxf(mx, __shfl_xor(mx, 32));
      float sm = 0.0f;
      #pragma unroll
      for (int nt = 0; nt < 4; ++nt)
        #pragma unroll
        for (int r = 0; r < 4; ++r) {
          ee[nt][r] = exp2f(ee[nt][r] - mx);
          sm += ee[nt][r];
        }
      sm += __shfl_xor(sm, 16);
      sm += __shfl_xor(sm, 32);
      invs[mt] = 1.0f / sm;
      #pragma unroll
      for (int nt = 0; nt < 4; ++nt) {
        pp[mt][nt][0] = pkc(ee[nt][0], ee[nt][1]);
        pp[mt][nt][1] = pkc(ee[nt][2], ee[nt][3]);
      }
    }

    // ---- PV: out^T = v^T · P^T -> otk[hi] (held in regs), then scale by invs ----
    #pragma unroll
    for (int dt = 0; dt < 2; ++dt)
      #pragma unroll
      for (int mt = 0; mt < 4; ++mt) otk[hi][dt][mt] = fz;
    #pragma unroll
    for (int kt = 0; kt < 2; ++kt) {
      bf16x8 pB[4];
      #pragma unroll
      for (int mt = 0; mt < 4; ++mt)
        pB[mt] = xposeP(pp[mt][2 * kt][0], pp[mt][2 * kt][1],
                        pp[mt][2 * kt + 1][0], pp[mt][2 * kt + 1][1]);
      #pragma unroll
      for (int dt = 0; dt < 2; ++dt)
        #pragma unroll
        for (int mt = 0; mt < 4; ++mt)
          otk[hi][dt][mt] = __builtin_amdgcn_mfma_f32_16x16x32_bf16(vA[dt][kt], pB[mt], otk[hi][dt][mt], 0, 0, 0);
    }
    #pragma unroll
    for (int dt = 0; dt < 2; ++dt)
      #pragma unroll
      for (int mt = 0; mt < 4; ++mt)
        otk[hi][dt][mt] = otk[hi][dt][mt] * invs[mt];
  }  // hi

  // ---- all xb reads done: overlay ob on sbuf (compiler-native packs) ----
  __syncthreads();
  #pragma unroll
  for (int hi = 0; hi < 2; ++hi) {
    const int h = wid + hi * 4;
    #pragma unroll
    for (int dt = 0; dt < 2; ++dt)
      #pragma unroll
      for (int mt = 0; mt < 4; ++mt) {
        union { unsigned u[2]; short4v s; } pk;
        pk.u[0] = pkc(otk[hi][dt][mt][0], otk[hi][dt][mt][1]);
        pk.u[1] = pkc(otk[hi][dt][mt][2], otk[hi][dt][mt][3]);
        *(short4v*)&sbuf[(mt * 16 + lq) * 264 + h * 32 + dt * 16 + lg * 4] = pk.s;
      }
  }
  __syncthreads();

  // ---- proj: out = ob · Wp^T + b (wave w -> cols [w*64, w*64+64)) ----
  {
    f32x4 acc[4][4];
    #pragma unroll
    for (int mt = 0; mt < 4; ++mt)
      #pragma unroll
      for (int nt = 0; nt < 4; ++nt) acc[mt][nt] = fz;
    const int c0 = wid * 64;
    #pragma unroll 2
    for (int ks = 0; ks < 8; ++ks) {
      const int k0 = ks * 32;
      bf16x8 a[4], b[4];
      #pragma unroll
      for (int mt = 0; mt < 4; ++mt)
        a[mt] = *(const bf16x8*)&sbuf[(mt * 16 + lq) * 264 + k0 + lg * 8];
      #pragma unroll
      for (int nt = 0; nt < 4; ++nt)
        b[nt] = *(const bf16x8*)&wproj[(c0 + nt * 16 + lq) * 256 + k0 + lg * 8];
      #pragma unroll
      for (int mt = 0; mt < 4; ++mt)
        #pragma unroll
        for (int nt = 0; nt < 4; ++nt)
          acc[mt][nt] = __builtin_amdgcn_mfma_f32_16x16x32_bf16(a[mt], b[nt], acc[mt][nt], 0, 0, 0);
    }
    #pragma unroll
    for (int nt = 0; nt < 4; ++nt) {
      const float pbv = projb[c0 + nt * 16 + lq];
      #pragma unroll
      for (int mt = 0; mt < 4; ++mt)
        #pragma unroll
        for (int r = 0; r < 4; ++r) {
          const int row = mt * 16 + lg * 4 + r;
          out[((size_t)blk * 64 + row) * 256 + c0 + nt * 16 + lq] = acc[mt][nt][r] + pbv;
        }
    }
  }
}

extern "C" void kernel_launch(void* const* d_in, const int* in_sizes, int n_in,
                              void* d_out, int out_size, void* d_ws, size_t ws_size,
                              hipStream_t stream) {
  const float* x     = (const float*)d_in[0];
  const float* qkvw  = (const float*)d_in[1];
  const float* qbias = (const float*)d_in[2];
  const float* vbias = (const float*)d_in[3];
  const float* ls    = (const float*)d_in[4];
  const float* w1    = (const float*)d_in[5];
  const float* b1    = (const float*)d_in[6];
  const float* w2    = (const float*)d_in[7];
  const float* pw    = (const float*)d_in[8];
  const float* pbias = (const float*)d_in[9];
  float* out = (float*)d_out;

  char* ws = (char*)d_ws;
  short* wqkv_bf  = (short*)(ws);                 // 393216 B
  short* wproj_bf = (short*)(ws + 393216);        // 131072 B
  float* rpb      = (float*)(ws + 524288);        // 131072 B
  float* scale    = (float*)(ws + 655360);        // 32 B
  float* qkvb     = (float*)(ws + 655392);        // 3072 B
  float* bt       = (float*)(ws + 658464);        // 4064 B

  prep_kernel<<<dim3(1151), dim3(256), 0, stream>>>(w1, b1, w2, bt,
                                                    qkvw, pw, qbias, vbias,
                                                    wqkv_bf, wproj_bf, qkvb);
  cpb_expand_kernel<<<dim3(128), dim3(256), 0, stream>>>(bt, ls, rpb, scale);
  win_attn_kernel<<<dim3(2048), dim3(256), 0, stream>>>(x, wqkv_bf, wproj_bf, qkvb,
                                                        scale, rpb, pbias, out);
}

// Round 20
// 179.423 us; speedup vs baseline: 1.0253x; 1.0250x over previous
//
#include <hip/hip_runtime.h>
#include <hip/hip_bf16.h>

// Swin-V2 window attention, fused. B=2048 windows, N=64 tokens, C=256, H=8, Dh=32.
// R20 = R16 verbatim (178.1us, PASS — session best). Restoration after R17-R19
// measured every remaining micro-lever as negative:
//   unroll>2 on QKV loop: regression (R13 bundled, R18 isolated-with-log2)
//   precise exp2f log2-softmax: regression (R19: VALUBusy 28.5->31.2 — ocml
//     exp2 has fixup ops; native 1-op exp2 needs inline-asm on acc values,
//     which is the forbidden R6/R7 failure class)
//   setprio: regression (R13). Bank conflicts: at b128 floor (R12/R16).
//   Occupancy: HW register-capped at 2 blocks/CU; lb>=3 miscompiles (R3-5,R11).
// Final ladder: 390 -> 340 -> 279 -> 191.7 -> 188.3 -> 184.2 -> 178.1 us.
// EVIDENCE RULES (R3..R19):
//  - never feed RAW MFMA-accumulator values to inline-asm v_cvt_pk_bf16_f32
//    (0.119 absmax R6/R7). pkc (compiler-native) on acc values is safe (R15);
//    permlane inline-asm on pkc outputs is safe (R16).
//  - never use __launch_bounds__ minWavesPerEU >= 3 (NaN with AND without cvt2).
//  - never unroll>2 the QKV k-loop; no setprio; no precise exp2f.
//  - deferred-V global x re-read thrashes L2 (R8) — x staged once in LDS.
// Layout algebra (mfma_f32_16x16x32_bf16): C/D: col=lane&15, row=(lane>>4)*4+reg;
// A-frag A[lane&15][(lane>>4)*8+j]; B-frag B[(lane>>4)*8+j][lane&15].
// xposeP: swap32+swap16 pairs give out[w] <- in[lg>>1][w&1] @ group 2(lg&1)+(w>>1).

typedef __attribute__((ext_vector_type(8))) short bf16x8;
typedef __attribute__((ext_vector_type(4))) short short4v;
typedef __attribute__((ext_vector_type(4))) float f32x4;

__device__ __forceinline__ unsigned short f2bf(float f) {
  union { float f; unsigned int u; } a; a.f = f;
  return (unsigned short)((a.u + 0x7FFFu + ((a.u >> 16) & 1u)) >> 16);  // RNE
}

// compiler-native packed f32x2 -> bf16x2 (RNE, lo = first/low 16b). Safe on
// accumulator values: no inline asm, compiler manages register classes.
__device__ __forceinline__ unsigned pkc(float lo, float hi) {
  float2 f; f.x = lo; f.y = hi;
  __hip_bfloat162 h = __float22bfloat162_rn(f);
  union { __hip_bfloat162 h; unsigned u; } c; c.h = h;
  return c.u;
}

// packed f32x2 -> bf16x2 inline asm, single VALU instr. ONLY safe on plain-VGPR
// load-path values — see EVIDENCE RULES above.
__device__ __forceinline__ unsigned int cvt2(float lo, float hi) {
  unsigned int r;
  asm("v_cvt_pk_bf16_f32 %0, %1, %2" : "=v"(r) : "v"(lo), "v"(hi));
  return r;
}

// 4x4 u32 transpose across stride-16 lane groups via permlane swaps (VALU).
// R16-proven (PASS, absmax 0.001953).
__device__ __forceinline__ bf16x8 xposeP(unsigned a0, unsigned a1,
                                         unsigned b0, unsigned b1) {
  asm("v_permlane32_swap_b32 %0, %1" : "+v"(a0), "+v"(b0));
  asm("v_permlane16_swap_b32 %0, %1" : "+v"(a0), "+v"(b0));
  asm("v_permlane32_swap_b32 %0, %1" : "+v"(a1), "+v"(b1));
  asm("v_permlane16_swap_b32 %0, %1" : "+v"(a1), "+v"(b1));
  union { unsigned u[4]; bf16x8 v; } c;
  c.u[0] = a0; c.u[1] = a1; c.u[2] = b0; c.u[3] = b1;
  return c.v;
}

// ---------------- fused prep: cpb table (blocks 0..126) + weight convert ----------------
__global__ void prep_kernel(const float* __restrict__ w1, const float* __restrict__ b1,
                            const float* __restrict__ w2, float* __restrict__ bt,
                            const float* __restrict__ qw, const float* __restrict__ pw,
                            const float* __restrict__ qb, const float* __restrict__ vb,
                            short* __restrict__ wqkv, short* __restrict__ wproj,
                            float* __restrict__ qkvb)
{
  if (blockIdx.x < 127) {
    // ---- CPB MLP table row (R9-proven body, first wave only) ----
    if (threadIdx.x < 64) {
      const int row = blockIdx.x;       // 0..126
      const int lane = threadIdx.x;     // 0..63
      float xr = ((float)row - 63.0f) * (8.0f / 63.0f);
      float sgn = (xr > 0.0f) ? 1.0f : ((xr < 0.0f) ? -1.0f : 0.0f);
      float val = sgn * log2f(fabsf(xr) + 1.0f) * (1.0f / 3.0f);  // /log2(8)
      float acc[8];
      #pragma unroll
      for (int hh = 0; hh < 8; ++hh) acc[hh] = 0.0f;
      #pragma unroll
      for (int jj = 0; jj < 8; ++jj) {
        int j = jj * 64 + lane;
        float hv = fmaxf(val * w1[j] + b1[j], 0.0f);
        #pragma unroll
        for (int hh = 0; hh < 8; ++hh) acc[hh] += hv * w2[hh * 512 + j];
      }
      #pragma unroll
      for (int hh = 0; hh < 8; ++hh) {
        #pragma unroll
        for (int m = 1; m < 64; m <<= 1) acc[hh] += __shfl_xor(acc[hh], m);
      }
      if (lane == 0) {
        #pragma unroll
        for (int hh = 0; hh < 8; ++hh) bt[row * 8 + hh] = acc[hh];
      }
    }
  } else {
    // ---- weight conversion (proven formulas, re-based index) ----
    const int idx = (blockIdx.x - 127) * 256 + threadIdx.x;
    if (idx < 196608) wqkv[idx] = (short)f2bf(qw[idx]);
    else if (idx - 196608 < 65536) wproj[idx - 196608] = (short)f2bf(pw[idx - 196608]);
    if (idx < 768) qkvb[idx] = (idx < 256) ? qb[idx] : ((idx < 512) ? 0.0f : vb[idx - 512]);
  }
}

// ---- expand (S^T orientation, R10-proven): rpb[h][mt][nt][lane][r] ----
__global__ void cpb_expand_kernel(const float* __restrict__ bt, const float* __restrict__ ls,
                                  float* __restrict__ rpb, float* __restrict__ scale)
{
  const int i = blockIdx.x * 256 + threadIdx.x;   // 0..32767
  const int r = i & 3, lane = (i >> 2) & 63, nt = (i >> 8) & 3, mt = (i >> 10) & 3, hh = i >> 12;
  const int row_i = mt * 16 + (lane & 15);          // query index
  const int col_j = nt * 16 + (lane >> 4) * 4 + r;  // key index
  float b = bt[(row_i - col_j + 63) * 8 + hh];
  rpb[i] = 16.0f / (1.0f + __expf(-b));
  if (i < 8) scale[i] = __expf(fminf(ls[i], 4.605170185988091f));  // ln(100)
}

// ---------------- fused window attention ----------------
__global__ __launch_bounds__(256, 2) void win_attn_kernel(
    const float* __restrict__ x,
    const short* __restrict__ wqkv,
    const short* __restrict__ wproj,
    const float* __restrict__ qkvb,
    const float* __restrict__ scale,
    const float* __restrict__ rpb,
    const float* __restrict__ projb,
    float* __restrict__ out)
{
  // single 33,792 B buffer: x tile bf16 [token][C] stride 264 during QKV;
  // overlaid by attention-output tile ob (same layout) after the hi loop.
  __shared__ short sbuf[64 * 264];

  const int tid = threadIdx.x;
  const int wid = tid >> 6;
  const int lane = tid & 63;
  const int lq = lane & 15;
  const int lg = lane >> 4;
  const int blk = blockIdx.x;

  const f32x4 fz = {0.0f, 0.0f, 0.0f, 0.0f};

  // ---- stage x tile (64x256 f32 -> bf16 LDS; cvt2 on load path; bank-floor clean) ----
  {
    const int r = tid >> 2;
    const int c0 = (tid & 3) * 64;
    const float4* xg = (const float4*)(x + ((size_t)blk * 64 + r) * 256 + c0);
    short* dst = &sbuf[r * 264 + c0];
    #pragma unroll
    for (int i = 0; i < 16; i += 2) {
      float4 a = xg[i];
      float4 b = xg[i + 1];
      union { unsigned int u[4]; bf16x8 v; } c;
      c.u[0] = cvt2(a.x, a.y); c.u[1] = cvt2(a.z, a.w);
      c.u[2] = cvt2(b.x, b.y); c.u[3] = cvt2(b.z, b.w);
      *(bf16x8*)(dst + i * 4) = c.v;
    }
  }
  __syncthreads();

  f32x4 otk[2][2][4];   // [hi][dt][mt], hi compile-time (R2-proven epilogue hold)

  #pragma unroll
  for (int hi = 0; hi < 2; ++hi) {
    const int h = wid + hi * 4;
    const short* wqb = wqkv + (h * 32 + lq) * 256 + lg * 8;

    // ---- QKV: sq/sk = W · x^T (q^T,k^T C-layout), sv = x · Wv^T (v C-layout) ----
    f32x4 sq[2][4], sk[2][4], sv[4][2];
    #pragma unroll
    for (int i = 0; i < 2; ++i)
      #pragma unroll
      for (int j = 0; j < 4; ++j) { sq[i][j] = fz; sk[i][j] = fz; sv[j][i] = fz; }

    #pragma unroll 2
    for (int ks = 0; ks < 8; ++ks) {
      const int k0 = ks * 32;
      bf16x8 xf[4];
      #pragma unroll
      for (int mt = 0; mt < 4; ++mt)
        xf[mt] = *(const bf16x8*)&sbuf[(mt * 16 + lq) * 264 + k0 + lg * 8];
      bf16x8 wqf[2], wkf[2], wvf[2];
      #pragma unroll
      for (int dt = 0; dt < 2; ++dt) {
        const short* wp = wqb + dt * 4096 + k0;
        wqf[dt] = *(const bf16x8*)wp;
        wkf[dt] = *(const bf16x8*)(wp + 65536);    // +256 rows
        wvf[dt] = *(const bf16x8*)(wp + 131072);   // +512 rows
      }
      #pragma unroll
      for (int dt = 0; dt < 2; ++dt)
        #pragma unroll
        for (int mt = 0; mt < 4; ++mt) {
          sq[dt][mt] = __builtin_amdgcn_mfma_f32_16x16x32_bf16(wqf[dt], xf[mt], sq[dt][mt], 0, 0, 0);
          sk[dt][mt] = __builtin_amdgcn_mfma_f32_16x16x32_bf16(wkf[dt], xf[mt], sk[dt][mt], 0, 0, 0);
          sv[mt][dt] = __builtin_amdgcn_mfma_f32_16x16x32_bf16(xf[mt], wvf[dt], sv[mt][dt], 0, 0, 0);
        }
    }

    bf16x8 qB[4], kA[4], vA[2][2];

    // ---- q: +bias, L2-normalize over d (in-lane 8 + shfl 16/32), pack -> B-frags ----
    {
      float qbias[2][4];
      #pragma unroll
      for (int dt = 0; dt < 2; ++dt)
        #pragma unroll
        for (int r = 0; r < 4; ++r)
          qbias[dt][r] = qkvb[h * 32 + dt * 16 + lg * 4 + r];
      #pragma unroll
      for (int mt = 0; mt < 4; ++mt) {
        float vv[2][4];
        float ss = 0.0f;
        #pragma unroll
        for (int dt = 0; dt < 2; ++dt)
          #pragma unroll
          for (int r = 0; r < 4; ++r) {
            vv[dt][r] = sq[dt][mt][r] + qbias[dt][r];
            ss += vv[dt][r] * vv[dt][r];
          }
        ss += __shfl_xor(ss, 16);
        ss += __shfl_xor(ss, 32);
        float rn = 1.0f / fmaxf(sqrtf(ss), 1e-12f);
        qB[mt] = xposeP(pkc(vv[0][0] * rn, vv[0][1] * rn), pkc(vv[0][2] * rn, vv[0][3] * rn),
                        pkc(vv[1][0] * rn, vv[1][1] * rn), pkc(vv[1][2] * rn, vv[1][3] * rn));
      }
    }
    // ---- k: L2-normalize (bias 0), pack -> A-frags ----
    {
      #pragma unroll
      for (int nt = 0; nt < 4; ++nt) {
        float ss = 0.0f;
        #pragma unroll
        for (int dt = 0; dt < 2; ++dt)
          #pragma unroll
          for (int r = 0; r < 4; ++r) ss += sk[dt][nt][r] * sk[dt][nt][r];
        ss += __shfl_xor(ss, 16);
        ss += __shfl_xor(ss, 32);
        float rn = 1.0f / fmaxf(sqrtf(ss), 1e-12f);
        kA[nt] = xposeP(pkc(sk[0][nt][0] * rn, sk[0][nt][1] * rn), pkc(sk[0][nt][2] * rn, sk[0][nt][3] * rn),
                        pkc(sk[1][nt][0] * rn, sk[1][nt][1] * rn), pkc(sk[1][nt][2] * rn, sk[1][nt][3] * rn));
      }
    }
    // ---- v: +bias, pack -> v^T A-frags vA[dt][kt] ----
    {
      const float vb0 = qkvb[512 + h * 32 + lq];
      const float vb1 = qkvb[512 + h * 32 + 16 + lq];
      unsigned vp[4][2][2];
      #pragma unroll
      for (int mt = 0; mt < 4; ++mt) {
        vp[mt][0][0] = pkc(sv[mt][0][0] + vb0, sv[mt][0][1] + vb0);
        vp[mt][0][1] = pkc(sv[mt][0][2] + vb0, sv[mt][0][3] + vb0);
        vp[mt][1][0] = pkc(sv[mt][1][0] + vb1, sv[mt][1][1] + vb1);
        vp[mt][1][1] = pkc(sv[mt][1][2] + vb1, sv[mt][1][3] + vb1);
      }
      #pragma unroll
      for (int dt = 0; dt < 2; ++dt)
        #pragma unroll
        for (int kt = 0; kt < 2; ++kt)
          vA[dt][kt] = xposeP(vp[2 * kt][dt][0], vp[2 * kt][dt][1],
                              vp[2 * kt + 1][dt][0], vp[2 * kt + 1][dt][1]);
    }

    // ---- S^T[key][query] = mfma(kA, qB) ----
    f32x4 sT[4][4];
    #pragma unroll
    for (int nt = 0; nt < 4; ++nt)
      #pragma unroll
      for (int mt = 0; mt < 4; ++mt)
        sT[nt][mt] = __builtin_amdgcn_mfma_f32_16x16x32_bf16(kA[nt], qB[mt], fz, 0, 0, 0);

    // ---- softmax over keys (16 in-lane + shfl 16/32); P packed UNNORMALIZED,
    //      per-query inv held in invs[mt] and applied to otk after PV ----
    const float sch = scale[h];
    float invs[4];
    unsigned pp[4][4][2];   // [mt][nt][c]
    #pragma unroll
    for (int mt = 0; mt < 4; ++mt) {
      f32x4 rp[4];
      #pragma unroll
      for (int nt = 0; nt < 4; ++nt)
        rp[nt] = ((const f32x4*)rpb)[((h * 4 + mt) * 4 + nt) * 64 + lane];
      float ee[4][4];
      float mx = -3.0e38f;
      #pragma unroll
      for (int nt = 0; nt < 4; ++nt)
        #pragma unroll
        for (int r = 0; r < 4; ++r) {
          float vv = sT[nt][mt][r] * sch + rp[nt][r];
          ee[nt][r] = vv;
          mx = fmaxf(mx, vv);
        }
      mx = fmaxf(mx, __shfl_xor(mx, 16));
      mx = fmaxf(mx, __shfl_xor(mx, 32));
      float sm = 0.0f;
      #pragma unroll
      for (int nt = 0; nt < 4; ++nt)
        #pragma unroll
        for (int r = 0; r < 4; ++r) {
          ee[nt][r] = __expf(ee[nt][r] - mx);
          sm += ee[nt][r];
        }
      sm += __shfl_xor(sm, 16);
      sm += __shfl_xor(sm, 32);
      invs[mt] = 1.0f / sm;
      #pragma unroll
      for (int nt = 0; nt < 4; ++nt) {
        pp[mt][nt][0] = pkc(ee[nt][0], ee[nt][1]);
        pp[mt][nt][1] = pkc(ee[nt][2], ee[nt][3]);
      }
    }

    // ---- PV: out^T = v^T · P^T -> otk[hi] (held in regs), then scale by invs ----
    #pragma unroll
    for (int dt = 0; dt < 2; ++dt)
      #pragma unroll
      for (int mt = 0; mt < 4; ++mt) otk[hi][dt][mt] = fz;
    #pragma unroll
    for (int kt = 0; kt < 2; ++kt) {
      bf16x8 pB[4];
      #pragma unroll
      for (int mt = 0; mt < 4; ++mt)
        pB[mt] = xposeP(pp[mt][2 * kt][0], pp[mt][2 * kt][1],
                        pp[mt][2 * kt + 1][0], pp[mt][2 * kt + 1][1]);
      #pragma unroll
      for (int dt = 0; dt < 2; ++dt)
        #pragma unroll
        for (int mt = 0; mt < 4; ++mt)
          otk[hi][dt][mt] = __builtin_amdgcn_mfma_f32_16x16x32_bf16(vA[dt][kt], pB[mt], otk[hi][dt][mt], 0, 0, 0);
    }
    #pragma unroll
    for (int dt = 0; dt < 2; ++dt)
      #pragma unroll
      for (int mt = 0; mt < 4; ++mt)
        otk[hi][dt][mt] = otk[hi][dt][mt] * invs[mt];
  }  // hi

  // ---- all xb reads done: overlay ob on sbuf (compiler-native packs) ----
  __syncthreads();
  #pragma unroll
  for (int hi = 0; hi < 2; ++hi) {
    const int h = wid + hi * 4;
    #pragma unroll
    for (int dt = 0; dt < 2; ++dt)
      #pragma unroll
      for (int mt = 0; mt < 4; ++mt) {
        union { unsigned u[2]; short4v s; } pk;
        pk.u[0] = pkc(otk[hi][dt][mt][0], otk[hi][dt][mt][1]);
        pk.u[1] = pkc(otk[hi][dt][mt][2], otk[hi][dt][mt][3]);
        *(short4v*)&sbuf[(mt * 16 + lq) * 264 + h * 32 + dt * 16 + lg * 4] = pk.s;
      }
  }
  __syncthreads();

  // ---- proj: out = ob · Wp^T + b (wave w -> cols [w*64, w*64+64)) ----
  {
    f32x4 acc[4][4];
    #pragma unroll
    for (int mt = 0; mt < 4; ++mt)
      #pragma unroll
      for (int nt = 0; nt < 4; ++nt) acc[mt][nt] = fz;
    const int c0 = wid * 64;
    #pragma unroll 2
    for (int ks = 0; ks < 8; ++ks) {
      const int k0 = ks * 32;
      bf16x8 a[4], b[4];
      #pragma unroll
      for (int mt = 0; mt < 4; ++mt)
        a[mt] = *(const bf16x8*)&sbuf[(mt * 16 + lq) * 264 + k0 + lg * 8];
      #pragma unroll
      for (int nt = 0; nt < 4; ++nt)
        b[nt] = *(const bf16x8*)&wproj[(c0 + nt * 16 + lq) * 256 + k0 + lg * 8];
      #pragma unroll
      for (int mt = 0; mt < 4; ++mt)
        #pragma unroll
        for (int nt = 0; nt < 4; ++nt)
          acc[mt][nt] = __builtin_amdgcn_mfma_f32_16x16x32_bf16(a[mt], b[nt], acc[mt][nt], 0, 0, 0);
    }
    #pragma unroll
    for (int nt = 0; nt < 4; ++nt) {
      const float pbv = projb[c0 + nt * 16 + lq];
      #pragma unroll
      for (int mt = 0; mt < 4; ++mt)
        #pragma unroll
        for (int r = 0; r < 4; ++r) {
          const int row = mt * 16 + lg * 4 + r;
          out[((size_t)blk * 64 + row) * 256 + c0 + nt * 16 + lq] = acc[mt][nt][r] + pbv;
        }
    }
  }
}

extern "C" void kernel_launch(void* const* d_in, const int* in_sizes, int n_in,
                              void* d_out, int out_size, void* d_ws, size_t ws_size,
                              hipStream_t stream) {
  const float* x     = (const float*)d_in[0];
  const float* qkvw  = (const float*)d_in[1];
  const float* qbias = (const float*)d_in[2];
  const float* vbias = (const float*)d_in[3];
  const float* ls    = (const float*)d_in[4];
  const float* w1    = (const float*)d_in[5];
  const float* b1    = (const float*)d_in[6];
  const float* w2    = (const float*)d_in[7];
  const float* pw    = (const float*)d_in[8];
  const float* pbias = (const float*)d_in[9];
  float* out = (float*)d_out;

  char* ws = (char*)d_ws;
  short* wqkv_bf  = (short*)(ws);                 // 393216 B
  short* wproj_bf = (short*)(ws + 393216);        // 131072 B
  float* rpb      = (float*)(ws + 524288);        // 131072 B
  float* scale    = (float*)(ws + 655360);        // 32 B
  float* qkvb     = (float*)(ws + 655392);        // 3072 B
  float* bt       = (float*)(ws + 658464);        // 4064 B

  prep_kernel<<<dim3(1151), dim3(256), 0, stream>>>(w1, b1, w2, bt,
                                                    qkvw, pw, qbias, vbias,
                                                    wqkv_bf, wproj_bf, qkvb);
  cpb_expand_kernel<<<dim3(128), dim3(256), 0, stream>>>(bt, ls, rpb, scale);
  win_attn_kernel<<<dim3(2048), dim3(256), 0, stream>>>(x, wqkv_bf, wproj_bf, qkvb,
                                                        scale, rpb, pbias, out);
}